// Round 2
// baseline (2274.689 us; speedup 1.0000x reference)
//
#include <hip/hip_runtime.h>
#include <hip/hip_bf16.h>
#include <stdint.h>

// LevelReasoning on MI355X — split-bf16 (bf16x3) precision build.
// h stored as hi/lo bf16 planes (f32-equivalent). GEMMs: 3-MFMA split scheme.
// Per layer: stats -> fold BN into Wqk; qk-GEMM (f32 out); attn-mix computes
// att (f32) and y = att@xn (split planes, y_hi on d_out); v-GEMM y@(gam*Wv).T
// with fused residual(+bias+xn)+ReLU epilogue updating h planes IN PLACE.
// Final GEMM plain bf16.

using bf16 = __hip_bfloat16;
typedef __attribute__((ext_vector_type(8))) short short8;
typedef __attribute__((ext_vector_type(4))) float f32x4;

static constexpr int KDIM = 512;

__device__ inline uint16_t f2b_bits(float f) {
  bf16 h = __float2bfloat16(f);
  return __builtin_bit_cast(uint16_t, h);
}
__device__ inline float b2f_bits(uint16_t u) { return __uint_as_float(((uint32_t)u) << 16); }
__device__ inline float bflo(uint32_t u) { return __uint_as_float((u & 0xffffu) << 16); }
__device__ inline float bfhi(uint32_t u) { return __uint_as_float(u & 0xffff0000u); }
__device__ inline void split2(float v, uint16_t& hi, uint16_t& lo) {
  hi = f2b_bits(v);
  lo = f2b_bits(v - b2f_bits(hi));
}

typedef const __attribute__((address_space(1))) void* gas_ptr;
typedef __attribute__((address_space(3))) void* las_ptr;
__device__ inline void gload16(const void* g, void* l) {
  __builtin_amdgcn_global_load_lds((gas_ptr)g, (las_ptr)l, 16, 0, 0);
}

// ---------------- f32 -> bf16 (plain) ----------------
__global__ __launch_bounds__(256) void cvt4(const float* __restrict__ in,
                                            bf16* __restrict__ out, int n4) {
  int i = blockIdx.x * 256 + threadIdx.x;
  const int stride = gridDim.x * 256;
  for (; i < n4; i += stride) {
    float4 v = ((const float4*)in)[i];
    uint32_t lo = (uint32_t)f2b_bits(v.x) | ((uint32_t)f2b_bits(v.y) << 16);
    uint32_t hi = (uint32_t)f2b_bits(v.z) | ((uint32_t)f2b_bits(v.w) << 16);
    ((uint2*)out)[i] = make_uint2(lo, hi);
  }
}

// ---------------- f32 -> hi/lo bf16 planes ----------------
__global__ __launch_bounds__(256) void split_cvt(const float* __restrict__ in,
                                                 bf16* __restrict__ hip,
                                                 bf16* __restrict__ lop, int n4) {
  int i = blockIdx.x * 256 + threadIdx.x;
  const int stride = gridDim.x * 256;
  for (; i < n4; i += stride) {
    float4 v = ((const float4*)in)[i];
    uint16_t h0, l0, h1, l1, h2, l2, h3, l3;
    split2(v.x, h0, l0); split2(v.y, h1, l1); split2(v.z, h2, l2); split2(v.w, h3, l3);
    ((uint2*)hip)[i] = make_uint2((uint32_t)h0 | ((uint32_t)h1 << 16),
                                  (uint32_t)h2 | ((uint32_t)h3 << 16));
    ((uint2*)lop)[i] = make_uint2((uint32_t)l0 | ((uint32_t)l1 << 16),
                                  (uint32_t)l2 | ((uint32_t)l3 << 16));
  }
}

// ---------------- split GEMM: out[M,N] = (Ahi+Alo)[M,512] @ (Whi+Wlo)[N,512]^T ----------------
// EPI 0: outf = acc + bias  (f32, pitch N)
// EPI 1: h planes = split(acc + bias)          (pitch 512)
// EPI 2: h planes = split(relu(acc + bias + (h)*s + t))  in place (pitch 512)
template <int EPI>
__global__ __launch_bounds__(256) void gemm_split(
    const bf16* __restrict__ Ahi, const bf16* __restrict__ Alo,
    const bf16* __restrict__ Whi, const bf16* __restrict__ Wlo,
    const float* __restrict__ bias, float* __restrict__ outf, int N,
    bf16* __restrict__ Ohi, bf16* __restrict__ Olo,
    const float* __restrict__ sv, const float* __restrict__ tv) {
  __shared__ __align__(16) char lds[32768];  // Ahi | Alo | Bhi | Blo (8KB each)
  const int tid = threadIdx.x;
  const int w = tid >> 6, l = tid & 63;
  const int bn = blockIdx.x * 128, bm = blockIdx.y * 128;

  const size_t rowA = (size_t)(bm + (l >> 2)) * KDIM;
  const size_t rowB = (size_t)(bn + (l >> 2)) * KDIM;
  const int ib = (l & 3) * 16;
  const char* Ah = (const char*)(Ahi + rowA) + ib;
  const char* Al = (const char*)(Alo + rowA) + ib;
  const char* Bh = (const char*)(Whi + rowB) + ib;
  const char* Bl = (const char*)(Wlo + rowB) + ib;

  const int lrow = l & 15, lk = l >> 4;
  const int wr = w >> 1, wc = w & 1;  // 2x2 wave grid, 64x64 per wave
  const int aoff = (wr * 64 + lrow) * 64 + lk * 16;
  const int boff = (wc * 64 + lrow) * 64 + lk * 16;

  f32x4 acc[4][4] = {};

  for (int k0 = 0; k0 < KDIM; k0 += 32) {
#pragma unroll
    for (int c = 0; c < 2; ++c) {
      const int ch = w + c * 4;  // 8 chunks of 1KB per plane tile
      const size_t so = (size_t)ch * 16 * (KDIM * 2) + k0 * 2;
      gload16(Ah + so, lds + ch * 1024);
      gload16(Al + so, lds + 8192 + ch * 1024);
      gload16(Bh + so, lds + 16384 + ch * 1024);
      gload16(Bl + so, lds + 24576 + ch * 1024);
    }
    __syncthreads();
    short8 ah[4], al[4], bh[4], bl[4];
#pragma unroll
    for (int i = 0; i < 4; ++i) {
      ah[i] = *(const short8*)(lds + aoff + i * 1024);
      al[i] = *(const short8*)(lds + 8192 + aoff + i * 1024);
      bh[i] = *(const short8*)(lds + 16384 + boff + i * 1024);
      bl[i] = *(const short8*)(lds + 24576 + boff + i * 1024);
    }
#pragma unroll
    for (int mi = 0; mi < 4; ++mi)
#pragma unroll
      for (int ni = 0; ni < 4; ++ni) {
        acc[mi][ni] = __builtin_amdgcn_mfma_f32_16x16x32_bf16(ah[mi], bh[ni], acc[mi][ni], 0, 0, 0);
        acc[mi][ni] = __builtin_amdgcn_mfma_f32_16x16x32_bf16(ah[mi], bl[ni], acc[mi][ni], 0, 0, 0);
        acc[mi][ni] = __builtin_amdgcn_mfma_f32_16x16x32_bf16(al[mi], bh[ni], acc[mi][ni], 0, 0, 0);
      }
    __syncthreads();
  }

#pragma unroll
  for (int mi = 0; mi < 4; ++mi) {
    const int row = bm + wr * 64 + mi * 16 + lk * 4;
#pragma unroll
    for (int ni = 0; ni < 4; ++ni) {
      const int col = bn + wc * 64 + ni * 16 + lrow;
      const float bc = bias[col];
      if (EPI == 0) {
#pragma unroll
        for (int j = 0; j < 4; ++j) outf[(size_t)(row + j) * N + col] = acc[mi][ni][j] + bc;
      } else if (EPI == 1) {
#pragma unroll
        for (int j = 0; j < 4; ++j) {
          const size_t idx = (size_t)(row + j) * 512 + col;
          uint16_t h, lo2;
          split2(acc[mi][ni][j] + bc, h, lo2);
          Ohi[idx] = __builtin_bit_cast(bf16, h);
          Olo[idx] = __builtin_bit_cast(bf16, lo2);
        }
      } else {
        const float sc = sv[col], tc = tv[col];
#pragma unroll
        for (int j = 0; j < 4; ++j) {
          const size_t idx = (size_t)(row + j) * 512 + col;
          const float xn = (__bfloat162float(Ohi[idx]) + __bfloat162float(Olo[idx])) * sc + tc;
          const float val = fmaxf(acc[mi][ni][j] + bc + xn, 0.f);
          uint16_t h, lo2;
          split2(val, h, lo2);
          Ohi[idx] = __builtin_bit_cast(bf16, h);
          Olo[idx] = __builtin_bit_cast(bf16, lo2);
        }
      }
    }
  }
}

// ---------------- plain bf16 GEMM (final layer only) ----------------
__global__ __launch_bounds__(256) void gemm_bt_f32(const bf16* __restrict__ A,
                                                   const bf16* __restrict__ W,
                                                   const float* __restrict__ bias,
                                                   float* __restrict__ out, int N) {
  __shared__ __align__(16) char lds[16384];
  const int tid = threadIdx.x;
  const int w = tid >> 6, l = tid & 63;
  const int bn = blockIdx.x * 128, bm = blockIdx.y * 128;

  const char* Ab = (const char*)(A + (size_t)(bm + (l >> 2)) * KDIM) + (l & 3) * 16;
  const char* Bb = (const char*)(W + (size_t)(bn + (l >> 2)) * KDIM) + (l & 3) * 16;

  const int lrow = l & 15, lk = l >> 4;
  const int wr = w >> 1, wc = w & 1;
  const int aoff = (wr * 64 + lrow) * 64 + lk * 16;
  const int boff = 8192 + (wc * 64 + lrow) * 64 + lk * 16;

  f32x4 acc[4][4] = {};
  for (int k0 = 0; k0 < KDIM; k0 += 32) {
#pragma unroll
    for (int c = 0; c < 2; ++c) {
      const int ch = w + c * 4;
      gload16(Ab + (size_t)ch * 16 * (KDIM * 2) + k0 * 2, lds + ch * 1024);
      gload16(Bb + (size_t)ch * 16 * (KDIM * 2) + k0 * 2, lds + 8192 + ch * 1024);
    }
    __syncthreads();
    short8 af[4], bfr[4];
#pragma unroll
    for (int i = 0; i < 4; ++i) af[i] = *(const short8*)(lds + aoff + i * 1024);
#pragma unroll
    for (int i = 0; i < 4; ++i) bfr[i] = *(const short8*)(lds + boff + i * 1024);
#pragma unroll
    for (int mi = 0; mi < 4; ++mi)
#pragma unroll
      for (int ni = 0; ni < 4; ++ni)
        acc[mi][ni] = __builtin_amdgcn_mfma_f32_16x16x32_bf16(af[mi], bfr[ni], acc[mi][ni], 0, 0, 0);
    __syncthreads();
  }
#pragma unroll
  for (int mi = 0; mi < 4; ++mi) {
    const int row = bm + wr * 64 + mi * 16 + lk * 4;
#pragma unroll
    for (int ni = 0; ni < 4; ++ni) {
      const int col = bn + wc * 64 + ni * 16 + lrow;
      const float bc = bias[col];
#pragma unroll
      for (int j = 0; j < 4; ++j)
        out[(size_t)(row + j) * N + col] = acc[mi][ni][j] + bc;
    }
  }
}

// ---------------- BN stats ----------------
__global__ __launch_bounds__(256) void stats_partial2(const bf16* __restrict__ hi,
                                                      const bf16* __restrict__ lo,
                                                      float* __restrict__ part) {
  const int c = threadIdx.x * 2;
  const int r0 = blockIdx.x * 224;
  float s0 = 0.f, q0 = 0.f, s1 = 0.f, q1 = 0.f;
  for (int r = r0; r < r0 + 224; ++r) {
    const size_t idx = (size_t)r * 512 + c;
    uint32_t uh = *(const uint32_t*)&hi[idx];
    uint32_t ul = *(const uint32_t*)&lo[idx];
    float a = bflo(uh) + bflo(ul), b = bfhi(uh) + bfhi(ul);
    s0 += a; q0 += a * a; s1 += b; q1 += b * b;
  }
  float* p = part + (size_t)blockIdx.x * 1024;
  p[c] = s0; p[c + 1] = s1;
  p[512 + c] = q0; p[512 + c + 1] = q1;
}

__global__ __launch_bounds__(64) void reduce_stats(const float* __restrict__ part,
                                                   const float* __restrict__ g,
                                                   const float* __restrict__ bb,
                                                   float* __restrict__ sv,
                                                   float* __restrict__ tv) {
  const int c = blockIdx.x, k = threadIdx.x;
  float sum = 0.f, sq = 0.f;
#pragma unroll
  for (int j = 0; j < 8; ++j) {
    const float* p = part + (size_t)(k + 64 * j) * 1024;
    sum += p[c]; sq += p[512 + c];
  }
#pragma unroll
  for (int o = 32; o; o >>= 1) { sum += __shfl_xor(sum, o); sq += __shfl_xor(sq, o); }
  if (k == 0) {
    const float mean = sum * (1.0f / 114688.0f);
    const float var = sq * (1.0f / 114688.0f) - mean * mean;
    const float sc = g[c] * rsqrtf(var + 1e-5f);
    sv[c] = sc;
    tv[c] = bb[c] - mean * sc;
  }
}

// ---------------- fold BN into q/k weight: W' = split(W*s), b' = b + t@W.T ----------------
__global__ __launch_bounds__(512) void fold_wqk_split(const float* __restrict__ Wsrc,
                                                      const float* __restrict__ bsrc,
                                                      const float* __restrict__ sv,
                                                      const float* __restrict__ tv,
                                                      bf16* __restrict__ Whi,
                                                      bf16* __restrict__ Wlo,
                                                      float* __restrict__ bdst) {
  const int row = blockIdx.x, c = threadIdx.x;
  __shared__ float red[512];
  const float wv = Wsrc[(size_t)row * 512 + c];
  uint16_t h, lo;
  split2(wv * sv[c], h, lo);
  Whi[(size_t)row * 512 + c] = __builtin_bit_cast(bf16, h);
  Wlo[(size_t)row * 512 + c] = __builtin_bit_cast(bf16, lo);
  red[c] = wv * tv[c];
  __syncthreads();
#pragma unroll
  for (int off = 256; off > 0; off >>= 1) {
    if (c < off) red[c] += red[c + off];
    __syncthreads();
  }
  if (c == 0) bdst[row] = bsrc[row] + red[0];
}

// ---------------- v weight: W' = split(gam*W), b' = gam*b (no BN fold; A is y=att@xn) --------
__global__ __launch_bounds__(512) void fold_wv_split(const float* __restrict__ Wsrc,
                                                     const float* __restrict__ bsrc,
                                                     const float* __restrict__ gamp,
                                                     bf16* __restrict__ Whi,
                                                     bf16* __restrict__ Wlo,
                                                     float* __restrict__ bdst) {
  const int row = blockIdx.x, c = threadIdx.x;
  const float gam = gamp[0];
  uint16_t h, lo;
  split2(Wsrc[(size_t)row * 512 + c] * gam, h, lo);
  Whi[(size_t)row * 512 + c] = __builtin_bit_cast(bf16, h);
  Wlo[(size_t)row * 512 + c] = __builtin_bit_cast(bf16, lo);
  if (c == 0) bdst[row] = gam * bsrc[row];
}

// ---------------- attention mix: att = softmax(qk^T) f32; y = att @ xn (split out) ----------
__global__ __launch_bounds__(256) void attn_mix(const float* __restrict__ qkf,
                                                const bf16* __restrict__ Hhi,
                                                const bf16* __restrict__ Hlo,
                                                const float* __restrict__ sv,
                                                const float* __restrict__ tv,
                                                bf16* __restrict__ Yhi,
                                                bf16* __restrict__ Ylo) {
  const int w = threadIdx.x >> 6, l = threadIdx.x & 63;
  const int b = blockIdx.x * 4 + w;
  const size_t base = (size_t)b * 7;

  float qv[7], kv[7];
#pragma unroll
  for (int i = 0; i < 7; ++i) {
    qv[i] = qkf[(base + i) * 128 + l];
    kv[i] = qkf[(base + i) * 128 + 64 + l];
  }
  float att[7][7];
#pragma unroll
  for (int i = 0; i < 7; ++i)
#pragma unroll
    for (int j = 0; j < 7; ++j) {
      float p = qv[i] * kv[j];
#pragma unroll
      for (int o = 32; o; o >>= 1) p += __shfl_xor(p, o);
      att[i][j] = p;
    }
#pragma unroll
  for (int i = 0; i < 7; ++i) {
    float m = att[i][0];
#pragma unroll
    for (int j = 1; j < 7; ++j) m = fmaxf(m, att[i][j]);
    float sum = 0.f;
#pragma unroll
    for (int j = 0; j < 7; ++j) { att[i][j] = expf(att[i][j] - m); sum += att[i][j]; }
    const float inv = 1.0f / sum;
#pragma unroll
    for (int j = 0; j < 7; ++j) att[i][j] *= inv;
  }
#pragma unroll
  for (int cc = 0; cc < 4; ++cc) {
    const int c = cc * 128 + l * 2;
    const float s0 = sv[c], s1 = sv[c + 1], t0 = tv[c], t1 = tv[c + 1];
    float x0[7], x1[7];
#pragma unroll
    for (int j = 0; j < 7; ++j) {
      const size_t idx = (base + j) * 512 + c;
      uint32_t uh = *(const uint32_t*)&Hhi[idx];
      uint32_t ul = *(const uint32_t*)&Hlo[idx];
      x0[j] = (bflo(uh) + bflo(ul)) * s0 + t0;
      x1[j] = (bfhi(uh) + bfhi(ul)) * s1 + t1;
    }
#pragma unroll
    for (int i = 0; i < 7; ++i) {
      float y0 = 0.f, y1 = 0.f;
#pragma unroll
      for (int j = 0; j < 7; ++j) { y0 += att[i][j] * x0[j]; y1 += att[i][j] * x1[j]; }
      const size_t idx = (base + i) * 512 + c;
      uint16_t h0, l0, h1, l1;
      split2(y0, h0, l0); split2(y1, h1, l1);
      *(uint32_t*)&Yhi[idx] = (uint32_t)h0 | ((uint32_t)h1 << 16);
      *(uint32_t*)&Ylo[idx] = (uint32_t)l0 | ((uint32_t)l1 << 16);
    }
  }
}

extern "C" void kernel_launch(void* const* d_in, const int* in_sizes, int n_in,
                              void* d_out, int out_size, void* d_ws, size_t ws_size,
                              hipStream_t stream) {
  const float* x  = (const float*)d_in[0];
  const float* Wt = (const float*)d_in[1];
  const float* bt = (const float*)d_in[2];
  const float *bng[3], *bnb[3], *Wq[3], *bq[3], *Wk[3], *bk[3], *Wv[3], *bv[3], *gam[3];
  for (int i = 0; i < 3; ++i) {
    int o = 3 + 9 * i;
    bng[i] = (const float*)d_in[o + 0];
    bnb[i] = (const float*)d_in[o + 1];
    Wq[i]  = (const float*)d_in[o + 2];
    bq[i]  = (const float*)d_in[o + 3];
    Wk[i]  = (const float*)d_in[o + 4];
    bk[i]  = (const float*)d_in[o + 5];
    Wv[i]  = (const float*)d_in[o + 6];
    bv[i]  = (const float*)d_in[o + 7];
    gam[i] = (const float*)d_in[o + 8];
  }
  const float* Wb = (const float*)d_in[30];
  const float* bb = (const float*)d_in[31];

  char* ws = (char*)d_ws;
  const size_t PL = 117440512;  // one plane: 114688*512*2 bytes
  bf16*  Hhi  = (bf16*)(ws);
  bf16*  Hlo  = (bf16*)(ws + PL);
  float* qkf  = (float*)(ws + 2 * PL);             // 58,720,256 B
  float* part = (float*)(ws + 293601280);          // 2,097,152 B
  float* sv   = (float*)(ws + 295698432);
  float* tv   = (float*)(ws + 295700480);
  bf16*  Wqkh = (bf16*)(ws + 295702528);           // 131,072
  bf16*  Wqkl = (bf16*)(ws + 295833600);           // 131,072
  float* bqkf = (float*)(ws + 295964672);          // 512
  bf16*  Wvh  = (bf16*)(ws + 295965184);           // 524,288
  bf16*  Wvl  = (bf16*)(ws + 296489472);           // 524,288
  float* bvf  = (float*)(ws + 297013760);          // 2,048
  bf16*  Wth  = (bf16*)(ws + 297015808);           // 524,288
  bf16*  Wtl  = (bf16*)(ws + 297540096);           // 524,288
  bf16*  Wbbf = (bf16*)(ws + 298064384);           // 262,144
  bf16*  Ylo  = (bf16*)(ws + 298326528);           // 117,440,512 (also x_lo)
  bf16*  Yhi  = (bf16*)d_out;                      // 117,440,512 == out bytes (also x_hi)

  // input / weight conversion
  split_cvt<<<2048, 256, 0, stream>>>(x, Yhi, Ylo, 14680064);   // x -> hi/lo planes
  split_cvt<<<256, 256, 0, stream>>>(Wt, Wth, Wtl, 65536);
  cvt4<<<128, 256, 0, stream>>>(Wb, Wbbf, 32768);

  // h0 = x @ Wt.T + bt  (split GEMM, h planes out)
  gemm_split<1><<<dim3(4, 896), 256, 0, stream>>>(Yhi, Ylo, Wth, Wtl, bt,
                                                  nullptr, 512, Hhi, Hlo, nullptr, nullptr);

  for (int i = 0; i < 3; ++i) {
    stats_partial2<<<512, 256, 0, stream>>>(Hhi, Hlo, part);
    reduce_stats<<<512, 64, 0, stream>>>(part, bng[i], bnb[i], sv, tv);
    fold_wqk_split<<<64, 512, 0, stream>>>(Wq[i], bq[i], sv, tv, Wqkh, Wqkl, bqkf);
    fold_wqk_split<<<64, 512, 0, stream>>>(Wk[i], bk[i], sv, tv,
                                           Wqkh + (size_t)64 * 512, Wqkl + (size_t)64 * 512,
                                           bqkf + 64);
    fold_wv_split<<<512, 512, 0, stream>>>(Wv[i], bv[i], gam[i], Wvh, Wvl, bvf);
    // q|k = h @ Wqk'.T + bqk'  (f32 out)
    gemm_split<0><<<dim3(1, 896), 256, 0, stream>>>(Hhi, Hlo, Wqkh, Wqkl, bqkf,
                                                    qkf, 128, nullptr, nullptr, nullptr, nullptr);
    // att + y = att@xn
    attn_mix<<<4096, 256, 0, stream>>>(qkf, Hhi, Hlo, sv, tv, Yhi, Ylo);
    // h = relu(y @ (gam*Wv).T + gam*bv + xn)   (in-place h update)
    gemm_split<2><<<dim3(4, 896), 256, 0, stream>>>(Yhi, Ylo, Wvh, Wvl, bvf,
                                                    nullptr, 512, Hhi, Hlo, sv, tv);
  }

  // out = h3 @ Wb.T + bb  (plain bf16 GEMM, f32 out)
  gemm_bt_f32<<<dim3(2, 896), 256, 0, stream>>>(Hhi, Wbbf, bb, (float*)d_out, 256);
}

// Round 3
// 1739.839 us; speedup vs baseline: 1.3074x; 1.3074x over previous
//
#include <hip/hip_runtime.h>
#include <hip/hip_bf16.h>
#include <stdint.h>

// LevelReasoning on MI355X — round 3.
// i-format activations: row = 512 ch = 32 chunks x 32B {8 bf16 hi | 8 bf16 lo}.
// All split GEMMs: 2-phase pipelined, 128B-coalesced global_load_lds staging,
// XOR slot swizzle (2-way banks), 3-MFMA split-bf16, one barrier per k-step.
// Layer: stats -> fold BN(+gam) into Wqk/Wv -> qk-GEMM(f32 on d_out) ->
//        v-GEMM(plain bf16) -> fused attn+residual+relu in-place on h.

using bf16 = __hip_bfloat16;
typedef __attribute__((ext_vector_type(8))) short short8;
typedef __attribute__((ext_vector_type(4))) float f32x4;

__device__ inline uint16_t f2b_bits(float f) {
  bf16 h = __float2bfloat16(f);
  return __builtin_bit_cast(uint16_t, h);
}
__device__ inline float b2f_bits(uint16_t u) { return __uint_as_float(((uint32_t)u) << 16); }
__device__ inline float bflo(uint32_t u) { return __uint_as_float((u & 0xffffu) << 16); }
__device__ inline float bfhi(uint32_t u) { return __uint_as_float(u & 0xffff0000u); }
__device__ inline void split2(float v, uint16_t& hi, uint16_t& lo) {
  hi = f2b_bits(v);
  lo = f2b_bits(v - b2f_bits(hi));
}
__device__ inline float h16(const uint4& u, int e) {
  uint32_t wrd = ((const uint32_t*)&u)[e >> 1];
  return (e & 1) ? bfhi(wrd) : bflo(wrd);
}

typedef const __attribute__((address_space(1))) void* gas_ptr;
typedef __attribute__((address_space(3))) void* las_ptr;
__device__ inline void gload16(const void* g, void* l) {
  __builtin_amdgcn_global_load_lds((gas_ptr)g, (las_ptr)l, 16, 0, 0);
}

// ---------------- f32 -> bf16 (plain, for Wb) ----------------
__global__ __launch_bounds__(256) void cvt4(const float* __restrict__ in,
                                            bf16* __restrict__ out, int n4) {
  int i = blockIdx.x * 256 + threadIdx.x;
  const int stride = gridDim.x * 256;
  for (; i < n4; i += stride) {
    float4 v = ((const float4*)in)[i];
    uint32_t lo = (uint32_t)f2b_bits(v.x) | ((uint32_t)f2b_bits(v.y) << 16);
    uint32_t hi = (uint32_t)f2b_bits(v.z) | ((uint32_t)f2b_bits(v.w) << 16);
    ((uint2*)out)[i] = make_uint2(lo, hi);
  }
}

// ---------------- fold weight to io-format: W' = g*W*diag(s), b' = g*(b + t@W.T) ----------------
__global__ __launch_bounds__(512) void fold_w_io(const float* __restrict__ Wsrc,
                                                 const float* __restrict__ bsrc,
                                                 const float* __restrict__ sv,
                                                 const float* __restrict__ tv,
                                                 const float* __restrict__ gamp,
                                                 char* __restrict__ Wio,
                                                 float* __restrict__ bout) {
  const int row = blockIdx.x, c = threadIdx.x;
  __shared__ float red[512];
  const float wv = Wsrc[(size_t)row * 512 + c];
  const float g = gamp ? gamp[0] : 1.0f;
  const float s = sv ? sv[c] : 1.0f;
  uint16_t hb, lb;
  split2(g * wv * s, hb, lb);
  char* p = Wio + (size_t)row * 2048 + (c >> 3) * 32 + (c & 7) * 2;
  *(uint16_t*)p = hb;
  *(uint16_t*)(p + 16) = lb;
  red[c] = tv ? wv * tv[c] : 0.0f;
  __syncthreads();
#pragma unroll
  for (int off = 256; off > 0; off >>= 1) {
    if (c < off) red[c] += red[c + off];
    __syncthreads();
  }
  if (c == 0) bout[row] = g * (bsrc[row] + red[0]);
}

// ---------------- split GEMM, 2-phase pipelined ----------------
// AMODE 0: A = io-format split bf16 (2KB rows). AMODE 1: A = f32 (2KB rows), split in-reg.
// EPI 0: outf[row*N+col] = acc+bias. EPI 1: io-format split out (2KB rows).
// EPI 2: plain bf16 out, pitch 512.
template <int AMODE, int EPI>
__global__ __launch_bounds__(256) void split_gemm(const char* __restrict__ A,
                                                  const char* __restrict__ Wio,
                                                  const float* __restrict__ bias,
                                                  float* __restrict__ outf,
                                                  char* __restrict__ outb, int N) {
  __shared__ __align__(16) char lds[65536];  // 2 bufs x (A 16KB | B 16KB)
  const int tid = threadIdx.x;
  const int w = tid >> 6, l = tid & 63;
  const int bn = blockIdx.x * 128, bm = blockIdx.y * 128;

  // staging: per-lane inverse-swizzled global source (rule #21)
  const int srow = l >> 3;                          // 0..7 rows within 1KB chunk
  const int sswz = ((l & 7) ^ (srow & 7)) * 16;     // logical slot for phys slot l&7
  const char* Asrc = A + (size_t)(bm + srow) * 2048 + sswz;
  const char* Bsrc = Wio + (size_t)(bn + srow) * 2048 + sswz;

  // fragment read constants
  const int lrow = l & 15, lk = l >> 4;
  const int wr = w >> 1, wc = w & 1;                // 2x2 waves, 64x64 each
  const int abase = (wr * 64 + lrow) * 128;
  const int bbase = 16384 + (wc * 64 + lrow) * 128;
  const int shi = ((2 * lk) ^ (lrow & 7)) * 16;     // hi slot, swizzled
  const int slo = ((2 * lk + 1) ^ (lrow & 7)) * 16; // lo slot, swizzled

  f32x4 acc[4][4] = {};

  auto stage = [&](int buf, int t) {
#pragma unroll
    for (int c = 0; c < 4; ++c) {
      const int i = w * 4 + c;  // 16 chunks of 1KB per tile (8 rows each)
      const size_t go = (size_t)i * 16384 + (size_t)t * 128;
      gload16(Asrc + go, lds + buf * 32768 + i * 1024);
      gload16(Bsrc + go, lds + buf * 32768 + 16384 + i * 1024);
    }
  };

  stage(0, 0);
  __syncthreads();
  int cur = 0;
  for (int t = 0; t < 16; ++t) {
    if (t < 15) stage(cur ^ 1, t + 1);  // issue next tile first (pipeline)
    const char* bp = lds + cur * 32768;
    short8 ah[4], al[4], bh[4], bl[4];
#pragma unroll
    for (int i = 0; i < 4; ++i) {
      if (AMODE == 0) {
        ah[i] = *(const short8*)(bp + abase + i * 2048 + shi);
        al[i] = *(const short8*)(bp + abase + i * 2048 + slo);
      } else {
        float4 f0 = *(const float4*)(bp + abase + i * 2048 + shi);
        float4 f1 = *(const float4*)(bp + abase + i * 2048 + slo);
        float fv[8] = {f0.x, f0.y, f0.z, f0.w, f1.x, f1.y, f1.z, f1.w};
#pragma unroll
        for (int e = 0; e < 8; ++e) {
          uint16_t hb, lb;
          split2(fv[e], hb, lb);
          ah[i][e] = (short)hb;
          al[i][e] = (short)lb;
        }
      }
      bh[i] = *(const short8*)(bp + bbase + i * 2048 + shi);
      bl[i] = *(const short8*)(bp + bbase + i * 2048 + slo);
    }
#pragma unroll
    for (int mi = 0; mi < 4; ++mi)
#pragma unroll
      for (int ni = 0; ni < 4; ++ni) {
        acc[mi][ni] = __builtin_amdgcn_mfma_f32_16x16x32_bf16(ah[mi], bh[ni], acc[mi][ni], 0, 0, 0);
        acc[mi][ni] = __builtin_amdgcn_mfma_f32_16x16x32_bf16(ah[mi], bl[ni], acc[mi][ni], 0, 0, 0);
        acc[mi][ni] = __builtin_amdgcn_mfma_f32_16x16x32_bf16(al[mi], bh[ni], acc[mi][ni], 0, 0, 0);
      }
    __syncthreads();  // vmcnt(0): next-tile loads (hidden under compute) + reuse fence
    cur ^= 1;
  }

#pragma unroll
  for (int mi = 0; mi < 4; ++mi) {
    const int row = bm + wr * 64 + mi * 16 + lk * 4;
#pragma unroll
    for (int ni = 0; ni < 4; ++ni) {
      const int col = bn + wc * 64 + ni * 16 + lrow;
      const float bc = bias[col];
#pragma unroll
      for (int j = 0; j < 4; ++j) {
        const float vv = acc[mi][ni][j] + bc;
        if (EPI == 0) {
          outf[(size_t)(row + j) * N + col] = vv;
        } else if (EPI == 1) {
          uint16_t hb, lb;
          split2(vv, hb, lb);
          char* p = outb + (size_t)(row + j) * 2048 + (col >> 3) * 32 + (col & 7) * 2;
          *(uint16_t*)p = hb;
          *(uint16_t*)(p + 16) = lb;
        } else {
          ((bf16*)outb)[(size_t)(row + j) * 512 + col] = __float2bfloat16(vv);
        }
      }
    }
  }
}

// ---------------- final plain GEMM: out[M,256] = h_hi @ Wb.T + bb ----------------
__global__ __launch_bounds__(256) void gemm_final(const char* __restrict__ Aio,
                                                  const bf16* __restrict__ Wb,
                                                  const float* __restrict__ bias,
                                                  float* __restrict__ out) {
  __shared__ __align__(16) char lds[32768];  // 2 bufs x (A 8KB | B 8KB)
  const int tid = threadIdx.x, w = tid >> 6, l = tid & 63;
  const int bn = blockIdx.x * 128, bm = blockIdx.y * 128;

  const int srow = l >> 2;                       // 0..15 rows within 1KB chunk
  const int ss = (l & 3) ^ (srow & 3);           // swizzled logical slot
  const char* Asrc = Aio + (size_t)(bm + srow) * 2048 + ss * 32;  // hi chunks @32B stride
  const char* Bsrc = (const char*)Wb + (size_t)(bn + srow) * 1024 + ss * 16;

  const int lrow = l & 15, lk = l >> 4;
  const int wr = w >> 1, wc = w & 1;
  const int abase = (wr * 64 + lrow) * 64;
  const int bbase = 8192 + (wc * 64 + lrow) * 64;
  const int sf = (lk ^ (lrow & 3)) * 16;

  f32x4 acc[4][4] = {};
  auto stage = [&](int buf, int t) {
#pragma unroll
    for (int c = 0; c < 2; ++c) {
      const int i = w * 2 + c;  // 8 chunks of 1KB (16 rows each)
      gload16(Asrc + (size_t)i * 16 * 2048 + (size_t)t * 128, lds + buf * 16384 + i * 1024);
      gload16(Bsrc + (size_t)i * 16 * 1024 + (size_t)t * 64, lds + buf * 16384 + 8192 + i * 1024);
    }
  };
  stage(0, 0);
  __syncthreads();
  int cur = 0;
  for (int t = 0; t < 16; ++t) {
    if (t < 15) stage(cur ^ 1, t + 1);
    const char* bp = lds + cur * 16384;
    short8 af[4], bf_[4];
#pragma unroll
    for (int i = 0; i < 4; ++i) {
      af[i] = *(const short8*)(bp + abase + i * 1024 + sf);
      bf_[i] = *(const short8*)(bp + bbase + i * 1024 + sf);
    }
#pragma unroll
    for (int mi = 0; mi < 4; ++mi)
#pragma unroll
      for (int ni = 0; ni < 4; ++ni)
        acc[mi][ni] = __builtin_amdgcn_mfma_f32_16x16x32_bf16(af[mi], bf_[ni], acc[mi][ni], 0, 0, 0);
    __syncthreads();
    cur ^= 1;
  }
#pragma unroll
  for (int mi = 0; mi < 4; ++mi) {
    const int row = bm + wr * 64 + mi * 16 + lk * 4;
#pragma unroll
    for (int ni = 0; ni < 4; ++ni) {
      const int col = bn + wc * 64 + ni * 16 + lrow;
      const float bc = bias[col];
#pragma unroll
      for (int j = 0; j < 4; ++j)
        out[(size_t)(row + j) * 256 + col] = acc[mi][ni][j] + bc;
    }
  }
}

// ---------------- BN stats on io-format h ----------------
__global__ __launch_bounds__(256) void stats_io(const char* __restrict__ Hio,
                                                float* __restrict__ part) {
  __shared__ float sm[4096];
  const int t = threadIdx.x;
  const int chunk = t & 63, grp = t >> 6;
  const int r0 = blockIdx.x * 448 + grp * 112;
  float s[8] = {}, q[8] = {};
  for (int r = r0; r < r0 + 112; ++r) {
    const char* p = Hio + (size_t)r * 2048 + chunk * 32;
    uint4 hh = *(const uint4*)p, hl = *(const uint4*)(p + 16);
#pragma unroll
    for (int e = 0; e < 8; ++e) {
      float v = h16(hh, e) + h16(hl, e);
      s[e] += v;
      q[e] += v * v;
    }
  }
#pragma unroll
  for (int e = 0; e < 8; ++e) {
    sm[grp * 512 + chunk * 8 + e] = s[e];
    sm[2048 + grp * 512 + chunk * 8 + e] = q[e];
  }
  __syncthreads();
  float* pb = part + (size_t)blockIdx.x * 1024;
#pragma unroll
  for (int cc = 0; cc < 2; ++cc) {
    const int c = t * 2 + cc;
    float ssum = sm[c] + sm[512 + c] + sm[1024 + c] + sm[1536 + c];
    float qsum = sm[2048 + c] + sm[2560 + c] + sm[3072 + c] + sm[3584 + c];
    pb[c] = ssum;
    pb[512 + c] = qsum;
  }
}

__global__ __launch_bounds__(64) void reduce_stats(const float* __restrict__ part,
                                                   const float* __restrict__ g,
                                                   const float* __restrict__ bb,
                                                   float* __restrict__ sv,
                                                   float* __restrict__ tv) {
  const int c = blockIdx.x, k = threadIdx.x;
  float sum = 0.f, sq = 0.f;
#pragma unroll
  for (int j = 0; j < 4; ++j) {
    const float* p = part + (size_t)(k + 64 * j) * 1024;
    sum += p[c];
    sq += p[512 + c];
  }
#pragma unroll
  for (int o = 32; o; o >>= 1) {
    sum += __shfl_xor(sum, o);
    sq += __shfl_xor(sq, o);
  }
  if (k == 0) {
    const float mean = sum * (1.0f / 114688.0f);
    const float var = sq * (1.0f / 114688.0f) - mean * mean;
    const float sc = g[c] * rsqrtf(var + 1e-5f);
    sv[c] = sc;
    tv[c] = bb[c] - mean * sc;
  }
}

// ---------------- fused attention + residual + relu, in place on h ----------------
// h_new = relu(att @ V + h*s + t)   (gamma already folded into V)
__global__ __launch_bounds__(256) void attn_relu(const float* __restrict__ qkf,
                                                 const bf16* __restrict__ V,
                                                 char* __restrict__ Hio,
                                                 const float* __restrict__ sv,
                                                 const float* __restrict__ tv) {
  const int w = threadIdx.x >> 6, l = threadIdx.x & 63;
  const int b = blockIdx.x * 4 + w;
  const size_t base = (size_t)b * 7;

  float qv[7], kv[7];
#pragma unroll
  for (int i = 0; i < 7; ++i) {
    qv[i] = qkf[(base + i) * 128 + l];
    kv[i] = qkf[(base + i) * 128 + 64 + l];
  }
  float att[7][7];
#pragma unroll
  for (int i = 0; i < 7; ++i)
#pragma unroll
    for (int j = 0; j < 7; ++j) {
      float p = qv[i] * kv[j];
#pragma unroll
      for (int o = 32; o; o >>= 1) p += __shfl_xor(p, o);
      att[i][j] = p;
    }
#pragma unroll
  for (int i = 0; i < 7; ++i) {
    float m = att[i][0];
#pragma unroll
    for (int j = 1; j < 7; ++j) m = fmaxf(m, att[i][j]);
    float sum = 0.f;
#pragma unroll
    for (int j = 0; j < 7; ++j) {
      att[i][j] = expf(att[i][j] - m);
      sum += att[i][j];
    }
    const float inv = 1.0f / sum;
#pragma unroll
    for (int j = 0; j < 7; ++j) att[i][j] *= inv;
  }

  // per-lane 8 channels: c0 = l*8
  const float4 s0 = *(const float4*)&sv[l * 8], s1 = *(const float4*)&sv[l * 8 + 4];
  const float4 t0 = *(const float4*)&tv[l * 8], t1 = *(const float4*)&tv[l * 8 + 4];
  const float sarr[8] = {s0.x, s0.y, s0.z, s0.w, s1.x, s1.y, s1.z, s1.w};
  const float tarr[8] = {t0.x, t0.y, t0.z, t0.w, t1.x, t1.y, t1.z, t1.w};

  uint4 vpk[7];
#pragma unroll
  for (int j = 0; j < 7; ++j)
    vpk[j] = *(const uint4*)((const char*)V + (base + j) * 1024 + l * 16);

#pragma unroll
  for (int i = 0; i < 7; ++i) {
    char* hp = Hio + (base + i) * 2048 + l * 32;
    uint4 hh = *(const uint4*)hp;
    uint4 hl = *(const uint4*)(hp + 16);
    float o[8] = {};
#pragma unroll
    for (int j = 0; j < 7; ++j) {
      const float a = att[i][j];
#pragma unroll
      for (int e = 0; e < 8; ++e) o[e] += a * h16(vpk[j], e);
    }
    uint16_t oh[8], ol[8];
#pragma unroll
    for (int e = 0; e < 8; ++e) {
      const float hval = h16(hh, e) + h16(hl, e);
      const float r = fmaxf(o[e] + hval * sarr[e] + tarr[e], 0.f);
      split2(r, oh[e], ol[e]);
    }
    uint4 ph, pl;
#pragma unroll
    for (int k2 = 0; k2 < 4; ++k2) {
      ((uint32_t*)&ph)[k2] = (uint32_t)oh[2 * k2] | ((uint32_t)oh[2 * k2 + 1] << 16);
      ((uint32_t*)&pl)[k2] = (uint32_t)ol[2 * k2] | ((uint32_t)ol[2 * k2 + 1] << 16);
    }
    *(uint4*)hp = ph;
    *(uint4*)(hp + 16) = pl;
  }
}

extern "C" void kernel_launch(void* const* d_in, const int* in_sizes, int n_in,
                              void* d_out, int out_size, void* d_ws, size_t ws_size,
                              hipStream_t stream) {
  const float* x  = (const float*)d_in[0];
  const float* Wt = (const float*)d_in[1];
  const float* bt = (const float*)d_in[2];
  const float *bng[3], *bnb[3], *Wq[3], *bq[3], *Wk[3], *bk[3], *Wv[3], *bv[3], *gam[3];
  for (int i = 0; i < 3; ++i) {
    int o = 3 + 9 * i;
    bng[i] = (const float*)d_in[o + 0];
    bnb[i] = (const float*)d_in[o + 1];
    Wq[i]  = (const float*)d_in[o + 2];
    bq[i]  = (const float*)d_in[o + 3];
    Wk[i]  = (const float*)d_in[o + 4];
    bk[i]  = (const float*)d_in[o + 5];
    Wv[i]  = (const float*)d_in[o + 6];
    bv[i]  = (const float*)d_in[o + 7];
    gam[i] = (const float*)d_in[o + 8];
  }
  const float* Wb = (const float*)d_in[30];
  const float* bb = (const float*)d_in[31];

  char* ws = (char*)d_ws;
  char*  Hio   = ws;                               // 235,929,600 (114688 x 2048B)
  char*  V     = ws + 235929600;                   // 117,440,512 (plain bf16)
  float* part  = (float*)(ws + 353370112);         // 1,048,576
  float* sv    = (float*)(ws + 354418688);         // 2,048
  float* tv    = (float*)(ws + 354420736);         // 2,048
  char*  WqkIo = ws + 354422784;                   // 262,144 (128 rows io)
  float* bqkf  = (float*)(ws + 354684928);         // 2,048
  char*  WvIo  = ws + 354686976;                   // 1,048,576 (512 rows io)
  float* bvf   = (float*)(ws + 355735552);         // 2,048
  char*  WtIo  = ws + 355737600;                   // 1,048,576
  float* btf   = (float*)(ws + 356786176);         // 2,048
  bf16*  Wbbf  = (bf16*)(ws + 356788224);          // 262,144
  float* qkf   = (float*)d_out;                    // 58,720,256 <= out bytes (117MB)

  // weight prep
  cvt4<<<128, 256, 0, stream>>>(Wb, Wbbf, 32768);
  fold_w_io<<<512, 512, 0, stream>>>(Wt, bt, nullptr, nullptr, nullptr, WtIo, btf);

  // h0 = x @ Wt.T + bt   (A = f32 x, split in-register; io out)
  split_gemm<1, 1><<<dim3(4, 896), 256, 0, stream>>>((const char*)x, WtIo, btf,
                                                     nullptr, Hio, 512);

  for (int i = 0; i < 3; ++i) {
    stats_io<<<256, 256, 0, stream>>>(Hio, part);
    reduce_stats<<<512, 64, 0, stream>>>(part, bng[i], bnb[i], sv, tv);
    fold_w_io<<<64, 512, 0, stream>>>(Wq[i], bq[i], sv, tv, nullptr, WqkIo, bqkf);
    fold_w_io<<<64, 512, 0, stream>>>(Wk[i], bk[i], sv, tv, nullptr,
                                      WqkIo + (size_t)64 * 2048, bqkf + 64);
    fold_w_io<<<512, 512, 0, stream>>>(Wv[i], bv[i], sv, tv, gam[i], WvIo, bvf);
    // q|k = h @ Wqk'.T + b'  (f32 out on d_out)
    split_gemm<0, 0><<<dim3(1, 896), 256, 0, stream>>>(Hio, WqkIo, bqkf, qkf, nullptr, 128);
    // v' = h @ (gam*Wv*s)'.T + b''  (plain bf16 out)
    split_gemm<0, 2><<<dim3(4, 896), 256, 0, stream>>>(Hio, WvIo, bvf, nullptr, V, 512);
    // h = relu(att@v' + h*s + t)  in place
    attn_relu<<<4096, 256, 0, stream>>>(qkf, (const bf16*)V, Hio, sv, tv);
  }

  // out = h3_hi @ Wb.T + bb
  gemm_final<<<dim3(2, 896), 256, 0, stream>>>(Hio, Wbbf, bb, (float*)d_out);
}